// Round 3
// baseline (178.544 us; speedup 1.0000x reference)
//
#include <hip/hip_runtime.h>
#include <stdint.h>

typedef _Float16 f16;
typedef f16 half8 __attribute__((ext_vector_type(8)));
typedef f16 half4 __attribute__((ext_vector_type(4)));
typedef float floatx4 __attribute__((ext_vector_type(4)));

#define MFMA_F16(A, B, Cc) __builtin_amdgcn_mfma_f32_16x16x32_f16((A), (B), (Cc), 0, 0, 0)

// Problem constants: B=4, H=W=64 -> N=4096, C=256, d=32
static constexpr int NB  = 4;
static constexpr int NN  = 4096;
static constexpr int NC  = 256;
static constexpr int ND  = 32;
static constexpr int PIX = NB * NN;  // 16384
static constexpr int NS  = 4;        // key splits
static constexpr int KS  = NN / NS;  // 1024 keys per split

// Device-global scratch. Fully rewritten every launch.
__device__ f16 g_WbT[320 * 256];              // [j][k]
__device__ f16 g_Qh[(size_t)PIX * ND];        // [row][32], pre-scaled by log2(e)
__device__ f16 g_Kh[(size_t)PIX * ND];        // [row][32]
__device__ f16 g_VbT[(size_t)NB * NC * NN];   // [b][c][n]
__device__ f16 g_Of[(size_t)NS * PIX * NC];   // per-split normalized O
__device__ float g_m[NS * PIX];               // per-split max (log2 domain)
__device__ float g_l[NS * PIX];               // per-split denom

__device__ inline void gl2lds16(const f16* g, f16* l) {
  __builtin_amdgcn_global_load_lds(
      (const __attribute__((address_space(1))) void*)g,
      (__attribute__((address_space(3))) void*)l, 16, 0, 0);
}

__device__ inline float max3f(float a, float b, float c) {
  return fmaxf(fmaxf(a, b), c);  // clang fuses to v_max3_f32
}

// ---------------------------------------------------------------------------
__global__ __launch_bounds__(256) void prep_weights(const float* __restrict__ wq,
                                                    const float* __restrict__ wk,
                                                    const float* __restrict__ wv) {
  const int tid = blockIdx.x * 256 + threadIdx.x;
  if (tid >= 320 * 256) return;
  const int j = tid >> 8;
  const int k = tid & 255;
  float v;
  if (j < 32)      v = wq[k * 32 + j];
  else if (j < 64) v = wk[k * 32 + (j - 32)];
  else             v = wv[k * 256 + (j - 64)];
  g_WbT[j * 256 + k] = (f16)v;
}

// ---------------------------------------------------------------------------
// QKV projection (unchanged). Q pre-scaled by log2(e).
__global__ __launch_bounds__(256) void proj_qkv(const float* __restrict__ x,
                                                const float* __restrict__ bq,
                                                const float* __restrict__ bk,
                                                const float* __restrict__ bv) {
  __shared__ f16 xs[64 * 32];
  __shared__ f16 wsT[320 * 32];
  __shared__ f16 vt[256 * 64];

  const int tid  = threadIdx.x;
  const int lane = tid & 63;
  const int wid  = tid >> 6;
  const int qd   = lane >> 4;
  const int c16  = lane & 15;
  const int p0   = blockIdx.x * 64;
  const floatx4 zero4 = {0.f, 0.f, 0.f, 0.f};

  floatx4 acc[20];
#pragma unroll
  for (int i = 0; i < 20; ++i) acc[i] = zero4;

  for (int kk = 0; kk < 256; kk += 32) {
    {
      const int r = tid >> 2, g = tid & 3;
      const floatx4* s4 = (const floatx4*)(x + (size_t)(p0 + r) * NC + kk + g * 8);
      const floatx4 xa = s4[0], xb = s4[1];
      half8 h;
      h[0] = (f16)xa[0]; h[1] = (f16)xa[1]; h[2] = (f16)xa[2]; h[3] = (f16)xa[3];
      h[4] = (f16)xb[0]; h[5] = (f16)xb[1]; h[6] = (f16)xb[2]; h[7] = (f16)xb[3];
      *(half8*)&xs[r * 32 + g * 8] = h;
    }
#pragma unroll
    for (int i = 0; i < 10; ++i) {
      const int cid = tid + 256 * i;
      const int j = cid >> 3, m = cid & 7;
      *(half4*)&wsT[j * 32 + m * 4] = *(const half4*)&g_WbT[j * 256 + kk + m * 4];
    }
    __syncthreads();
    const half8 a = *(const half8*)&xs[(wid * 16 + c16) * 32 + qd * 8];
#pragma unroll
    for (int nt = 0; nt < 20; ++nt) {
      const half8 bfr = *(const half8*)&wsT[(nt * 16 + c16) * 32 + qd * 8];
      acc[nt] = MFMA_F16(a, bfr, acc[nt]);
    }
    __syncthreads();
  }

#pragma unroll
  for (int nt = 0; nt < 20; ++nt) {
    const int j = nt * 16 + c16;
    const float bias = (j < 32) ? bq[j] : (j < 64) ? bk[j - 32] : bv[j - 64];
#pragma unroll
    for (int r = 0; r < 4; ++r) {
      const int rl = wid * 16 + qd * 4 + r;
      const int p  = p0 + rl;
      const float val = acc[nt][r] + bias;
      if (j < 32) {
        g_Qh[(size_t)p * ND + j] = (f16)(val * 1.44269504f);  // log2(e)
      } else if (j < 64) {
        g_Kh[(size_t)p * ND + (j - 32)] = (f16)val;
      } else {
        vt[(j - 64) * 64 + rl] = (f16)val;
      }
    }
  }
  __syncthreads();
  const int b  = p0 >> 12;
  const int n0 = p0 & (NN - 1);
#pragma unroll
  for (int i = 0; i < 16; ++i) {
    const int cid = tid + 256 * i;
    const int c = cid >> 4, m = cid & 15;
    *(half4*)(g_VbT + ((size_t)(b * NC + c)) * NN + n0 + m * 4) =
        *(const half4*)&vt[c * 64 + m * 4];
  }
}

// ---------------------------------------------------------------------------
// Flash attention, round-3: 2-stage software pipeline.
// Per iter t: [barrier] -> pa <- ps (P(t) into regs, frees ps) ->
// QK(t+1) MFMAs -> issue K(t+2) + stage V(t+1)->buf^1 ->
// softmax(t+1) (max/alpha/exp2/ps-write; acc-independent) ->
// PV(t) 64 MFMAs on vsT[buf] -> deferred acc-rescale (rare).
// softmax(t+1) and PV(t) are data-independent, so the scheduler can
// interleave VALU/TRANS/LDS with the MFMA burst (previously serialized).
// One barrier/iter; stage+K issued a full iter before their drain.
// Anti-phase: co-resident blocks (adjacent same-XCD wgids) start the
// K-ring 8 tiles apart (online softmax is order-independent) to
// decorrelate pipe bursts. XCD decode + chunk-XOR LDS swizzle unchanged.
__global__ __launch_bounds__(256, 2) void attn_split(void) {
  __shared__ f16 vsT[2][256 * 64];     // 64 KB  [buf][c][64 keys], chunk-swizzled
  __shared__ f16 ps[4][2][16 * 64];    // 16 KB  [wave][qgrp][q][64 keys], swizzled

  const int tid  = threadIdx.x;
  const int lane = tid & 63;
  const int wid  = tid >> 6;
  const int qd   = lane >> 4;
  const int c16  = lane & 15;

  // XCD-aware decode.
  const int wgid = blockIdx.x;
  const int xcd  = wgid & 7;
  const int rem  = wgid >> 3;
  const int xblk = rem & 31;
  const int ghi  = rem >> 5;
  const int g_bs = xcd | (ghi << 3);   // = b*4 + s
  const int b    = g_bs >> 2;
  const int s    = g_bs & 3;
  const int q0   = xblk * 128 + wid * 32;
  const int ph8  = (rem & 1) * 8;      // anti-phase K-ring offset

  const int sx7  = c16 & 7;
  const floatx4 zero4 = {0.f, 0.f, 0.f, 0.f};

  const int vrow = wid * 64 + (lane >> 3);
  const int vchk = (lane & 7) ^ ((lane >> 3) & 7);
  const f16* vlane = g_VbT + ((size_t)(b * NC + vrow)) * NN + vchk * 8;

  const int kbeg = s * KS;
  constexpr int NT = KS / 64;          // 16 tiles

  // K-ring: tile t -> key offset
  auto k_of = [&](int t) { return kbeg + ((t + ph8) & (NT - 1)) * 64; };
  auto stage = [&](int kt, int bu) {
    f16* vdst = &vsT[bu][(size_t)wid * 4096];
#pragma unroll
    for (int i = 0; i < 8; ++i)
      gl2lds16(vlane + kt + i * 8 * NN, vdst + i * 512);
  };

  half8 kreg[4];
  auto kload = [&](int kt) {
#pragma unroll
    for (int a = 0; a < 4; ++a)
      kreg[a] = *(const half8*)(g_Kh + ((size_t)(b * NN + kt + a * 16 + c16)) * ND + qd * 8);
  };

  // Q fragments (B-operand)
  half8 qf[2];
#pragma unroll
  for (int g = 0; g < 2; ++g)
    qf[g] = *(const half8*)(g_Qh + ((size_t)(b * NN + q0 + g * 16 + c16)) * ND + qd * 8);

  floatx4 acc[2][16];
#pragma unroll
  for (int g = 0; g < 2; ++g)
#pragma unroll
    for (int i = 0; i < 16; ++i) acc[g][i] = zero4;
  float m_i[2] = {-1e30f, -1e30f};
  float l_p[2] = {0.f, 0.f};

  // ---- prologue: K(0), V(0) in flight; QK(0); K(1); softmax(0) ----
  kload(k_of(0));
  stage(k_of(0), 0);
  {
    floatx4 st[2][4];
#pragma unroll
    for (int g = 0; g < 2; ++g)
#pragma unroll
      for (int a = 0; a < 4; ++a) st[g][a] = MFMA_F16(kreg[a], qf[g], zero4);
    kload(k_of(1));
#pragma unroll
    for (int g = 0; g < 2; ++g) {
      const floatx4* v = st[g];
      float ta = max3f(v[0][0], v[0][1], v[0][2]);
      float tb = max3f(v[0][3], v[1][0], v[1][1]);
      float tc = max3f(v[1][2], v[1][3], v[2][0]);
      float td = max3f(v[2][1], v[2][2], v[2][3]);
      float te = max3f(v[3][0], v[3][1], v[3][2]);
      float tr = fmaxf(max3f(ta, tb, tc), max3f(td, te, v[3][3]));
      tr = fmaxf(tr, __shfl_xor(tr, 16));
      tr = fmaxf(tr, __shfl_xor(tr, 32));
      m_i[g] = tr + 5.0f;
      float ts = 0.f;
#pragma unroll
      for (int a = 0; a < 4; ++a) {
        half4 h;
#pragma unroll
        for (int r = 0; r < 4; ++r) {
          const float p = exp2f(st[g][a][r] - m_i[g]);
          ts += p;
          h[r] = (f16)p;
        }
        const int pc = ((a * 2 + (qd >> 1)) ^ sx7) * 8 + (qd & 1) * 4;
        *(half4*)&ps[wid][g][c16 * 64 + pc] = h;
      }
      l_p[g] = ts;
    }
  }

  // ---- pipelined main loop: iters 0..NT-2 ----
  for (int t = 0; t < NT - 1; ++t) {
    const int buf = t & 1;
    __syncthreads();  // V(t) landed in vsT[buf]; vsT[buf^1] free; ps = P(t)

    // P(t) -> regs (frees ps for P(t+1))
    half8 pa[2][2];
#pragma unroll
    for (int g = 0; g < 2; ++g)
#pragma unroll
      for (int kh = 0; kh < 2; ++kh)
        pa[g][kh] = *(const half8*)&ps[wid][g][c16 * 64 + ((kh * 4 + qd) ^ sx7) * 8];

    // QK(t+1) from kreg (= K(t+1))
    floatx4 st[2][4];
#pragma unroll
    for (int g = 0; g < 2; ++g)
#pragma unroll
      for (int a = 0; a < 4; ++a) st[g][a] = MFMA_F16(kreg[a], qf[g], zero4);

    // issue K(t+2) and V(t+1) early: a full iteration of flight time
    kload(k_of(t + 2));
    stage(k_of(t + 1), buf ^ 1);

    // ---- softmax(t+1): max/alpha (acc-independent) ----
    float tm[2];
#pragma unroll
    for (int g = 0; g < 2; ++g) {
      const floatx4* v = st[g];
      float ta = max3f(v[0][0], v[0][1], v[0][2]);
      float tb = max3f(v[0][3], v[1][0], v[1][1]);
      float tc = max3f(v[1][2], v[1][3], v[2][0]);
      float td = max3f(v[2][1], v[2][2], v[2][3]);
      float te = max3f(v[3][0], v[3][1], v[3][2]);
      tm[g] = fmaxf(max3f(ta, tb, tc), max3f(td, te, v[3][3]));
    }
    const bool fire = __any(tm[0] > m_i[0] || tm[1] > m_i[1]);
    float a4[2][4];
    if (fire) {
#pragma unroll
      for (int g = 0; g < 2; ++g) {
        float tr = tm[g];
        tr = fmaxf(tr, __shfl_xor(tr, 16));
        tr = fmaxf(tr, __shfl_xor(tr, 32));
        const float m_new = (tr > m_i[g]) ? tr + 5.0f : m_i[g];
        const float alpha = exp2f(m_i[g] - m_new);
        m_i[g] = m_new;
        l_p[g] *= alpha;
#pragma unroll
        for (int r = 0; r < 4; ++r) a4[g][r] = __shfl(alpha, qd * 4 + r);
      }
    }

    // P(t+1) = exp2(s - m), ps write (ps free: pa captured above)
#pragma unroll
    for (int g = 0; g < 2; ++g) {
      float ts = 0.f;
#pragma unroll
      for (int a = 0; a < 4; ++a) {
        half4 h;
#pragma unroll
        for (int r = 0; r < 4; ++r) {
          const float p = exp2f(st[g][a][r] - m_i[g]);
          ts += p;
          h[r] = (f16)p;
        }
        const int pc = ((a * 2 + (qd >> 1)) ^ sx7) * 8 + (qd & 1) * 4;
        *(half4*)&ps[wid][g][c16 * 64 + pc] = h;
      }
      l_p[g] += ts;
    }

    // ---- PV(t): 64 MFMAs on vsT[buf] (scheduler interleaves softmax above) ----
    __builtin_amdgcn_s_setprio(1);
#pragma unroll
    for (int ct = 0; ct < 16; ++ct) {
#pragma unroll
      for (int kh = 0; kh < 2; ++kh) {
        const half8 bfr =
            *(const half8*)&vsT[buf][(ct * 16 + c16) * 64 + ((kh * 4 + qd) ^ sx7) * 8];
        acc[0][ct] = MFMA_F16(pa[0][kh], bfr, acc[0][ct]);
        acc[1][ct] = MFMA_F16(pa[1][kh], bfr, acc[1][ct]);
      }
    }
    __builtin_amdgcn_s_setprio(0);

    // ---- deferred rescale: acc now holds P(t)V(t); re-reference to m_new ----
    if (fire) {
#pragma unroll
      for (int g = 0; g < 2; ++g)
#pragma unroll
        for (int ct = 0; ct < 16; ++ct)
#pragma unroll
          for (int r = 0; r < 4; ++r) acc[g][ct][r] *= a4[g][r];
    }
  }

  // ---- peeled final iter: PV(NT-1) only ----
  {
    const int buf = (NT - 1) & 1;
    __syncthreads();
    half8 pa[2][2];
#pragma unroll
    for (int g = 0; g < 2; ++g)
#pragma unroll
      for (int kh = 0; kh < 2; ++kh)
        pa[g][kh] = *(const half8*)&ps[wid][g][c16 * 64 + ((kh * 4 + qd) ^ sx7) * 8];
    __builtin_amdgcn_s_setprio(1);
#pragma unroll
    for (int ct = 0; ct < 16; ++ct) {
#pragma unroll
      for (int kh = 0; kh < 2; ++kh) {
        const half8 bfr =
            *(const half8*)&vsT[buf][(ct * 16 + c16) * 64 + ((kh * 4 + qd) ^ sx7) * 8];
        acc[0][ct] = MFMA_F16(pa[0][kh], bfr, acc[0][ct]);
        acc[1][ct] = MFMA_F16(pa[1][kh], bfr, acc[1][ct]);
      }
    }
    __builtin_amdgcn_s_setprio(0);
  }

  // ---- epilogue ----
#pragma unroll
  for (int g = 0; g < 2; ++g) {
    float l = l_p[g];
    l += __shfl_xor(l, 16);
    l += __shfl_xor(l, 32);
    if (qd == 0) {
      const int row = b * NN + q0 + g * 16 + c16;
      g_m[s * PIX + row] = m_i[g];
      g_l[s * PIX + row] = l;
    }
    float linv[4];
#pragma unroll
    for (int r = 0; r < 4; ++r) linv[r] = 1.0f / __shfl(l, qd * 4 + r);
#pragma unroll
    for (int ct = 0; ct < 16; ++ct)
#pragma unroll
      for (int r = 0; r < 4; ++r) {
        const int qrow = q0 + g * 16 + qd * 4 + r;
        const int c = ct * 16 + c16;
        g_Of[((size_t)(s * PIX + b * NN + qrow)) * NC + c] = (f16)(acc[g][ct][r] * linv[r]);
      }
  }
}

// ---------------------------------------------------------------------------
// Merge NS partials (log2 domain): w_s = l_s * 2^(m_s - M) / den.
__global__ __launch_bounds__(256) void combine(const float* __restrict__ x,
                                               float* __restrict__ out) {
  const int tid  = threadIdx.x;
  const int lane = tid & 63;
  const int wid  = tid >> 6;
  const int row  = blockIdx.x * 4 + wid;
  const int c    = lane * 4;

  float m[NS], l[NS], M = -1e30f;
#pragma unroll
  for (int s = 0; s < NS; ++s) {
    m[s] = g_m[s * PIX + row];
    l[s] = g_l[s * PIX + row];
    M = fmaxf(M, m[s]);
  }
  float w[NS], den = 0.f;
#pragma unroll
  for (int s = 0; s < NS; ++s) { w[s] = l[s] * exp2f(m[s] - M); den += w[s]; }
  const float inv = 1.0f / den;

  float a0 = 0.f, a1 = 0.f, a2 = 0.f, a3 = 0.f;
#pragma unroll
  for (int s = 0; s < NS; ++s) {
    const half4 h = *(const half4*)&g_Of[((size_t)(s * PIX + row)) * NC + c];
    const float ws = w[s] * inv;
    a0 += ws * (float)h[0];
    a1 += ws * (float)h[1];
    a2 += ws * (float)h[2];
    a3 += ws * (float)h[3];
  }
  const floatx4 xv = *(const floatx4*)&x[(size_t)row * NC + c];
  floatx4 o;
  o[0] = a0 + xv[0]; o[1] = a1 + xv[1]; o[2] = a2 + xv[2]; o[3] = a3 + xv[3];
  *(floatx4*)&out[(size_t)row * NC + c] = o;
}

// ---------------------------------------------------------------------------
extern "C" void kernel_launch(void* const* d_in, const int* in_sizes, int n_in,
                              void* d_out, int out_size, void* d_ws, size_t ws_size,
                              hipStream_t stream) {
  (void)in_sizes; (void)n_in; (void)d_ws; (void)ws_size; (void)out_size;
  const float* x  = (const float*)d_in[0];
  const float* wq = (const float*)d_in[1];
  const float* bq = (const float*)d_in[2];
  const float* wk = (const float*)d_in[3];
  const float* bk = (const float*)d_in[4];
  const float* wv = (const float*)d_in[5];
  const float* bv = (const float*)d_in[6];
  float* out = (float*)d_out;

  hipLaunchKernelGGL(prep_weights, dim3(320), dim3(256), 0, stream, wq, wk, wv);
  hipLaunchKernelGGL(proj_qkv, dim3(256), dim3(256), 0, stream, x, bq, bk, bv);
  hipLaunchKernelGGL(attn_split, dim3(512), dim3(256), 0, stream);
  hipLaunchKernelGGL(combine, dim3(PIX / 4), dim3(256), 0, stream, x, out);
}

// Round 4
// 163.040 us; speedup vs baseline: 1.0951x; 1.0951x over previous
//
#include <hip/hip_runtime.h>
#include <stdint.h>

typedef _Float16 f16;
typedef f16 half8 __attribute__((ext_vector_type(8)));
typedef f16 half4 __attribute__((ext_vector_type(4)));
typedef float floatx4 __attribute__((ext_vector_type(4)));

#define MFMA_F16(A, B, Cc) __builtin_amdgcn_mfma_f32_16x16x32_f16((A), (B), (Cc), 0, 0, 0)

// Problem constants: B=4, H=W=64 -> N=4096, C=256, d=32
static constexpr int NB  = 4;
static constexpr int NN  = 4096;
static constexpr int NC  = 256;
static constexpr int ND  = 32;
static constexpr int PIX = NB * NN;  // 16384
static constexpr int NS  = 4;        // key splits
static constexpr int KS  = NN / NS;  // 1024 keys per split

// Device-global scratch. Fully rewritten every launch.
__device__ f16 g_WbT[320 * 256];              // [j][k]
__device__ f16 g_Qh[(size_t)PIX * ND];        // [row][32], pre-scaled by log2(e)
__device__ f16 g_Kh[(size_t)PIX * ND];        // [row][32]
__device__ f16 g_VbT[(size_t)NB * NC * NN];   // [b][c][n]
__device__ f16 g_Of[(size_t)NS * PIX * NC];   // per-split normalized O
__device__ float g_m[NS * PIX];               // per-split max (log2 domain)
__device__ float g_l[NS * PIX];               // per-split denom

__device__ inline void gl2lds16(const f16* g, f16* l) {
  __builtin_amdgcn_global_load_lds(
      (const __attribute__((address_space(1))) void*)g,
      (__attribute__((address_space(3))) void*)l, 16, 0, 0);
}

// ---------------------------------------------------------------------------
__global__ __launch_bounds__(256) void prep_weights(const float* __restrict__ wq,
                                                    const float* __restrict__ wk,
                                                    const float* __restrict__ wv) {
  const int tid = blockIdx.x * 256 + threadIdx.x;
  if (tid >= 320 * 256) return;
  const int j = tid >> 8;
  const int k = tid & 255;
  float v;
  if (j < 32)      v = wq[k * 32 + j];
  else if (j < 64) v = wk[k * 32 + (j - 32)];
  else             v = wv[k * 256 + (j - 64)];
  g_WbT[j * 256 + k] = (f16)v;
}

// ---------------------------------------------------------------------------
// QKV projection, round-4: j-dimension split across blockIdx.y.
// half 0: j 0..159   (Q: 0..31, K: 32..63, V cols 0..95)
// half 1: j 160..319 (V cols 96..255)
// Grid 256x2 -> 2 blocks/CU (was 1), acc 20->10 regs, LDS 34 KB.
// Cost: x is read twice (+16.8 MB HBM) to buy 2x latency hiding.
__global__ __launch_bounds__(256) void proj_qkv(const float* __restrict__ x,
                                                const float* __restrict__ bq,
                                                const float* __restrict__ bk,
                                                const float* __restrict__ bv) {
  __shared__ f16 xs[64 * 32];      // 4 KB
  __shared__ f16 wsT[160 * 32];    // 10 KB
  __shared__ f16 vt[160 * 64];     // 20 KB

  const int tid  = threadIdx.x;
  const int lane = tid & 63;
  const int wid  = tid >> 6;
  const int qd   = lane >> 4;
  const int c16  = lane & 15;
  const int p0   = blockIdx.x * 64;
  const int half = blockIdx.y;
  const int j0   = half * 160;
  const floatx4 zero4 = {0.f, 0.f, 0.f, 0.f};

  floatx4 acc[10];
#pragma unroll
  for (int i = 0; i < 10; ++i) acc[i] = zero4;

  for (int kk = 0; kk < 256; kk += 32) {
    {
      const int r = tid >> 2, g = tid & 3;
      const floatx4* s4 = (const floatx4*)(x + (size_t)(p0 + r) * NC + kk + g * 8);
      const floatx4 xa = s4[0], xb = s4[1];
      half8 h;
      h[0] = (f16)xa[0]; h[1] = (f16)xa[1]; h[2] = (f16)xa[2]; h[3] = (f16)xa[3];
      h[4] = (f16)xb[0]; h[5] = (f16)xb[1]; h[6] = (f16)xb[2]; h[7] = (f16)xb[3];
      *(half8*)&xs[r * 32 + g * 8] = h;
    }
#pragma unroll
    for (int i = 0; i < 5; ++i) {
      const int cid = tid + 256 * i;
      const int j = cid >> 3, m = cid & 7;  // j in [0,160)
      *(half4*)&wsT[j * 32 + m * 4] = *(const half4*)&g_WbT[(j0 + j) * 256 + kk + m * 4];
    }
    __syncthreads();
    const half8 a = *(const half8*)&xs[(wid * 16 + c16) * 32 + qd * 8];
#pragma unroll
    for (int nt = 0; nt < 10; ++nt) {
      const half8 bfr = *(const half8*)&wsT[(nt * 16 + c16) * 32 + qd * 8];
      acc[nt] = MFMA_F16(a, bfr, acc[nt]);
    }
    __syncthreads();
  }

#pragma unroll
  for (int nt = 0; nt < 10; ++nt) {
    const int j = j0 + nt * 16 + c16;
    const float bias = (j < 32) ? bq[j] : (j < 64) ? bk[j - 32] : bv[j - 64];
#pragma unroll
    for (int r = 0; r < 4; ++r) {
      const int rl = wid * 16 + qd * 4 + r;
      const int p  = p0 + rl;
      const float val = acc[nt][r] + bias;
      if (j < 32) {
        g_Qh[(size_t)p * ND + j] = (f16)(val * 1.44269504f);  // log2(e)
      } else if (j < 64) {
        g_Kh[(size_t)p * ND + (j - 32)] = (f16)val;
      } else {
        vt[(j - 64 - half * 96) * 64 + rl] = (f16)val;  // local V col
      }
    }
  }
  __syncthreads();
  const int b    = p0 >> 12;
  const int n0   = p0 & (NN - 1);
  const int ncol = half ? 160 : 96;
  const int c0   = half ? 96 : 0;
  const int nit  = (ncol * 16) >> 8;  // 6 or 10
  for (int i = 0; i < nit; ++i) {
    const int cid = tid + 256 * i;
    const int c = cid >> 4, m = cid & 15;
    *(half4*)(g_VbT + ((size_t)(b * NC + c0 + c)) * NN + n0 + m * 4) =
        *(const half4*)&vt[c * 64 + m * 4];
  }
}

// ---------------------------------------------------------------------------
// Flash attention: block = 128 q (4 waves x 32 q), K-tile = 64 keys,
// blockIdx.z = 1024-key split. K direct from global (reg double-buffer);
// V async global_load_lds into XOR-swizzled vsT; P via XOR-swizzled ps.
// Physical 16B chunk = logical chunk ^ (row & 7)  -> conflict-minimal LDS.
// (Reverted verbatim to the round-0 best: 70.8 us measured. R1/R2/R3
// restructurings — more blocks, dbuf+1-barrier+XCD-swizzle, SW pipeline —
// were all <= neutral; R2 proved the kernel is not HBM- or barrier-count
// bound, so this structure stands until a fundamentally different
// decomposition is justified.)
__global__ __launch_bounds__(256, 2) void attn_split(void) {
  __shared__ f16 vsT[256 * 64];        // 32 KB  [c][64 keys], chunk-swizzled
  __shared__ f16 ps[4][2][16 * 64];    // 16 KB  [wave][qgrp][q][64 keys], swizzled

  const int tid  = threadIdx.x;
  const int lane = tid & 63;
  const int wid  = tid >> 6;
  const int qd   = lane >> 4;
  const int c16  = lane & 15;
  const int b    = blockIdx.y;
  const int s    = blockIdx.z;
  const int q0   = blockIdx.x * 128 + wid * 32;
  const int sx7  = c16 & 7;  // row&7 for this lane's reads
  const floatx4 zero4 = {0.f, 0.f, 0.f, 0.f};

  // Per-lane V staging source: wave wid stages c rows [wid*64, wid*64+64).
  // LDS dest of gl_lds is wave-uniform base + lane*16 (lane-linear), so the
  // XOR swizzle is applied to the GLOBAL source chunk instead.
  const int vrow = wid * 64 + (lane >> 3);
  const int vchk = (lane & 7) ^ ((lane >> 3) & 7);
  const f16* vlane = g_VbT + ((size_t)(b * NC + vrow)) * NN + vchk * 8;
  f16* vdst = &vsT[(size_t)wid * 4096 + (size_t)0];  // + i*512 per instr

  // Q fragments (B-operand)
  half8 qf[2];
#pragma unroll
  for (int g = 0; g < 2; ++g)
    qf[g] = *(const half8*)(g_Qh + ((size_t)(b * NN + q0 + g * 16 + c16)) * ND + qd * 8);

  floatx4 acc[2][16];
#pragma unroll
  for (int g = 0; g < 2; ++g)
#pragma unroll
    for (int i = 0; i < 16; ++i) acc[g][i] = zero4;
  float m_i[2] = {-1e30f, -1e30f};
  float l_p[2] = {0.f, 0.f};

  const int kbeg = s * KS, kend = (s + 1) * KS;

  // prologue: V(kbeg) async -> LDS; K(kbeg) -> regs
#pragma unroll
  for (int i = 0; i < 8; ++i)
    gl2lds16(vlane + kbeg + i * 8 * NN, vdst + i * 512);
  half8 kreg[4];
#pragma unroll
  for (int a = 0; a < 4; ++a)
    kreg[a] = *(const half8*)(g_Kh + ((size_t)(b * NN + kbeg + a * 16 + c16)) * ND + qd * 8);

  for (int k0 = kbeg; k0 < kend; k0 += 64) {
    // ---- S^T = K * Q^T from registers (no LDS dependency) ----
    floatx4 st[2][4];
#pragma unroll
    for (int g = 0; g < 2; ++g)
#pragma unroll
      for (int a = 0; a < 4; ++a) st[g][a] = MFMA_F16(kreg[a], qf[g], zero4);

    // ---- lazy max (overshoot +5, log2 domain) ----
    float tm[2];
#pragma unroll
    for (int g = 0; g < 2; ++g) {
      float t0 = fmaxf(fmaxf(st[g][0][0], st[g][0][1]), fmaxf(st[g][0][2], st[g][0][3]));
      float t1 = fmaxf(fmaxf(st[g][1][0], st[g][1][1]), fmaxf(st[g][1][2], st[g][1][3]));
      float t2 = fmaxf(fmaxf(st[g][2][0], st[g][2][1]), fmaxf(st[g][2][2], st[g][2][3]));
      float t3 = fmaxf(fmaxf(st[g][3][0], st[g][3][1]), fmaxf(st[g][3][2], st[g][3][3]));
      tm[g] = fmaxf(fmaxf(t0, t1), fmaxf(t2, t3));
    }
    if (__any(tm[0] > m_i[0] || tm[1] > m_i[1])) {
#pragma unroll
      for (int g = 0; g < 2; ++g) {
        float tr = tm[g];
        tr = fmaxf(tr, __shfl_xor(tr, 16));
        tr = fmaxf(tr, __shfl_xor(tr, 32));
        const float m_new = (tr > m_i[g]) ? tr + 5.0f : m_i[g];
        const float alpha = exp2f(m_i[g] - m_new);
        m_i[g] = m_new;
        l_p[g] *= alpha;
        float a4[4];
#pragma unroll
        for (int r = 0; r < 4; ++r) a4[r] = __shfl(alpha, qd * 4 + r);
#pragma unroll
        for (int ct = 0; ct < 16; ++ct)
#pragma unroll
          for (int r = 0; r < 4; ++r) acc[g][ct][r] *= a4[r];
      }
    }

    // ---- P = exp2(s - m), per-lane partial l, swizzled ps write ----
    // key = a*16 + qd*4  -> chunk a*2+(qd>>1), sub-offset (qd&1)*4
#pragma unroll
    for (int g = 0; g < 2; ++g) {
      float ts = 0.f;
#pragma unroll
      for (int a = 0; a < 4; ++a) {
        half4 h;
#pragma unroll
        for (int r = 0; r < 4; ++r) {
          const float p = exp2f(st[g][a][r] - m_i[g]);
          ts += p;
          h[r] = (f16)p;
        }
        const int pc = ((a * 2 + (qd >> 1)) ^ sx7) * 8 + (qd & 1) * 4;
        *(half4*)&ps[wid][g][c16 * 64 + pc] = h;
      }
      l_p[g] += ts;
    }

    __syncthreads();  // [A] compiler drains vmcnt -> vsT(k0) landed everywhere

    // ---- prefetch K(next) into regs (latency covered by PV MFMAs) ----
    const int k0n = (k0 + 64 < kend) ? (k0 + 64) : kbeg;
    half8 knew[4];
#pragma unroll
    for (int a = 0; a < 4; ++a)
      knew[a] = *(const half8*)(g_Kh + ((size_t)(b * NN + k0n + a * 16 + c16)) * ND + qd * 8);

    // ---- PV: O += P * V, 64 MFMAs; swizzled reads ----
    half8 pa[2][2];
#pragma unroll
    for (int g = 0; g < 2; ++g)
#pragma unroll
      for (int kh = 0; kh < 2; ++kh)
        pa[g][kh] = *(const half8*)&ps[wid][g][c16 * 64 + ((kh * 4 + qd) ^ sx7) * 8];
#pragma unroll
    for (int ct = 0; ct < 16; ++ct) {
#pragma unroll
      for (int kh = 0; kh < 2; ++kh) {
        const half8 bfr =
            *(const half8*)&vsT[(ct * 16 + c16) * 64 + ((kh * 4 + qd) ^ sx7) * 8];
        acc[0][ct] = MFMA_F16(pa[0][kh], bfr, acc[0][ct]);
        acc[1][ct] = MFMA_F16(pa[1][kh], bfr, acc[1][ct]);
      }
    }
    __syncthreads();  // [B] all waves done reading vsT(k0)

    // ---- issue async V(k+1) -> LDS (in flight until next [A]) ----
    if (k0 + 64 < kend) {
#pragma unroll
      for (int i = 0; i < 8; ++i)
        gl2lds16(vlane + (k0 + 64) + i * 8 * NN, vdst + i * 512);
    }
#pragma unroll
    for (int a = 0; a < 4; ++a) kreg[a] = knew[a];
  }

  // ---- epilogue ----
#pragma unroll
  for (int g = 0; g < 2; ++g) {
    float l = l_p[g];
    l += __shfl_xor(l, 16);
    l += __shfl_xor(l, 32);
    if (qd == 0) {
      const int row = b * NN + q0 + g * 16 + c16;
      g_m[s * PIX + row] = m_i[g];
      g_l[s * PIX + row] = l;
    }
    float linv[4];
#pragma unroll
    for (int r = 0; r < 4; ++r) linv[r] = 1.0f / __shfl(l, qd * 4 + r);
#pragma unroll
    for (int ct = 0; ct < 16; ++ct)
#pragma unroll
      for (int r = 0; r < 4; ++r) {
        const int qrow = q0 + g * 16 + qd * 4 + r;
        const int c = ct * 16 + c16;
        g_Of[((size_t)(s * PIX + b * NN + qrow)) * NC + c] = (f16)(acc[g][ct][r] * linv[r]);
      }
  }
}

// ---------------------------------------------------------------------------
// Merge NS partials (log2 domain): w_s = l_s * 2^(m_s - M) / den.
// Round-4: 16B loads (half8 per split), 8 rows/block, grid PIX/8.
__global__ __launch_bounds__(256) void combine(const float* __restrict__ x,
                                               float* __restrict__ out) {
  const int tid  = threadIdx.x;
  const int lane = tid & 63;
  const int wid  = tid >> 6;
  const int row  = blockIdx.x * 8 + wid * 2 + (lane >> 5);
  const int c    = (lane & 31) * 8;

  float m[NS], l[NS], M = -1e30f;
#pragma unroll
  for (int s = 0; s < NS; ++s) {
    m[s] = g_m[s * PIX + row];
    l[s] = g_l[s * PIX + row];
    M = fmaxf(M, m[s]);
  }
  float w[NS], den = 0.f;
#pragma unroll
  for (int s = 0; s < NS; ++s) { w[s] = l[s] * exp2f(m[s] - M); den += w[s]; }
  const float inv = 1.0f / den;

  float a[8];
#pragma unroll
  for (int j = 0; j < 8; ++j) a[j] = 0.f;
#pragma unroll
  for (int s = 0; s < NS; ++s) {
    const half8 h = *(const half8*)&g_Of[((size_t)(s * PIX + row)) * NC + c];
    const float ws = w[s] * inv;
#pragma unroll
    for (int j = 0; j < 8; ++j) a[j] += ws * (float)h[j];
  }
  const floatx4 x0 = *(const floatx4*)&x[(size_t)row * NC + c];
  const floatx4 x1 = *(const floatx4*)&x[(size_t)row * NC + c + 4];
  floatx4 o0, o1;
#pragma unroll
  for (int j = 0; j < 4; ++j) { o0[j] = a[j] + x0[j]; o1[j] = a[j + 4] + x1[j]; }
  *(floatx4*)&out[(size_t)row * NC + c] = o0;
  *(floatx4*)&out[(size_t)row * NC + c + 4] = o1;
}

// ---------------------------------------------------------------------------
extern "C" void kernel_launch(void* const* d_in, const int* in_sizes, int n_in,
                              void* d_out, int out_size, void* d_ws, size_t ws_size,
                              hipStream_t stream) {
  (void)in_sizes; (void)n_in; (void)d_ws; (void)ws_size; (void)out_size;
  const float* x  = (const float*)d_in[0];
  const float* wq = (const float*)d_in[1];
  const float* bq = (const float*)d_in[2];
  const float* wk = (const float*)d_in[3];
  const float* bk = (const float*)d_in[4];
  const float* wv = (const float*)d_in[5];
  const float* bv = (const float*)d_in[6];
  float* out = (float*)d_out;

  hipLaunchKernelGGL(prep_weights, dim3(320), dim3(256), 0, stream, wq, wk, wv);
  hipLaunchKernelGGL(proj_qkv, dim3(256, 2), dim3(256), 0, stream, x, bq, bk, bv);
  hipLaunchKernelGGL(attn_split, dim3(NN / 128, NB, NS), dim3(256), 0, stream);
  hipLaunchKernelGGL(combine, dim3(PIX / 8), dim3(256), 0, stream, x, out);
}